// Round 3
// baseline (655.593 us; speedup 1.0000x reference)
//
#include <hip/hip_runtime.h>
#include <hip/hip_bf16.h>

// DenseRecurrentConsciousnessNet on MI355X (gfx950)
// B=65536, H=512, S=256, D=64.
// R5: occupancy 2 -> 4 blocks/CU. R4 counters showed 80% idle cycles with all
// pipes <13% busy at 22% occupancy -- every latency exposed, LDS (64KB) the
// binding cap. A is now staged in K-halves (one 32KB region, [row][q|c]
// layout, XOR-swizzled), 8 K-iters per half, restage between halves.
// LDS = max(32KB A, 38.7KB epilogue) = 38.9KB -> 4 blocks/CU.
// A-stage global loads made perfectly lane-contiguous (128B per row-octet).
// B direct-to-VGPR rolling prefetch, epilogue, PV, atomics unchanged from R4.

typedef short short8 __attribute__((ext_vector_type(8)));
typedef float floatx4 __attribute__((ext_vector_type(4)));
typedef unsigned uintx2 __attribute__((ext_vector_type(2)));

#define H_DIM 512
#define BM 32

// ws byte offsets
#define WS_WT    0          // bf16 [576][512]  = 589824 B
#define WS_MEMT  589824     // bf16 [64][256]   = 32768 B
#define WS_BFULL 622592     // f32  [576]       = 2304 B
#define WS_WSUM  624896     // f32  [256]       = 1024 B
#define WS_CSUM  625920     // f32  [64]        = 256 B

__device__ __forceinline__ unsigned short f2b(float f) {
  unsigned u = __float_as_uint(f);
  u += 0x7fffu + ((u >> 16) & 1u);          // round-to-nearest-even
  return (unsigned short)(u >> 16);
}
__device__ __forceinline__ float b2f(unsigned short h) {
  return __uint_as_float(((unsigned)h) << 16);
}
__device__ __forceinline__ unsigned cvt2(float x, float y) {
  union { __hip_bfloat162 h; unsigned u; } c;
  c.h = __float22bfloat162_rn(make_float2(x, y));
  return c.u;
}

__global__ void drcn_init(const float* __restrict__ W_read, const float* __restrict__ W_write,
                          const float* __restrict__ W_content, const float* __restrict__ b_read,
                          const float* __restrict__ b_write, const float* __restrict__ b_content,
                          const float* __restrict__ memory,
                          unsigned short* __restrict__ Wt, unsigned short* __restrict__ memT,
                          float* __restrict__ bfull, float* __restrict__ w_sum,
                          float* __restrict__ c_sum) {
  int idx = blockIdx.x * 256 + threadIdx.x;
  if (idx < 294912) {                       // Wt[n][k] = W[k][n], bf16
    int n = idx >> 9, k = idx & 511;
    float v;
    if (n < 256)      v = W_read[k * 256 + n];
    else if (n < 512) v = W_write[k * 256 + (n - 256)];
    else              v = W_content[k * 64 + (n - 512)];
    Wt[idx] = f2b(v);
  } else if (idx < 311296) {                // memT[d][s] = memory[s][d], bf16
    int i = idx - 294912;
    int d = i >> 8, s = i & 255;
    memT[i] = f2b(memory[s * 64 + d]);
  } else if (idx < 311872) {                // packed bias [576]
    int n = idx - 311296;
    bfull[n] = (n < 256) ? b_read[n] : (n < 512 ? b_write[n - 256] : b_content[n - 512]);
  } else if (idx < 312192) {                // zero accumulators
    int i = idx - 311872;
    if (i < 256) w_sum[i] = 0.0f; else c_sum[i - 256] = 0.0f;
  }
}

__global__ __launch_bounds__(256, 4) void drcn_main(
    const float* __restrict__ query, const float* __restrict__ content,
    const unsigned short* __restrict__ Wt, const float* __restrict__ bfull,
    const unsigned short* __restrict__ memT, float* __restrict__ w_sum,
    float* __restrict__ c_sum, float* __restrict__ out) {
  // LDS phases:
  //   K-loop : A half-tile [32 rows][1024 B] = q(512B) | c(512B), swizzled.
  //   epilog : lg[32][584] bf16 (37376) | cs[256] f32 @37376 | cp[64] f32 @38400
  __shared__ __align__(16) char smem[38912];
  unsigned short* lg = (unsigned short*)smem;
  float* cs = (float*)(smem + 37376);
  float* cp = (float*)(smem + 38400);

  const int t = threadIdx.x;
  const int wv = t >> 6;
  const int ln = t & 63;
  const int ln15 = ln & 15;
  const int quad = ln >> 4;
  const int m0 = blockIdx.x * BM;

  // ---- B: direct global->VGPR, per-lane frag pointers + iter-0 loads ----
  // frag(j, it): Wt[(wv*9+j)*16 + ln15][it*32 + quad*8 .. +8]
  const unsigned short* bp[9];
  short8 breg[9];
  #pragma unroll
  for (int j = 0; j < 9; j++) {
    bp[j] = Wt + (size_t)(((wv * 9 + j) * 16 + ln15) * 512 + quad * 8);
    breg[j] = *(const short8*)bp[j];
  }

  float bias[9];
  #pragma unroll
  for (int j = 0; j < 9; j++) bias[j] = bfull[(wv * 9 + j) * 16 + ln15];

  floatx4 acc[2][9];
  #pragma unroll
  for (int mt = 0; mt < 2; mt++)
    #pragma unroll
    for (int j = 0; j < 9; j++) {
      floatx4 z = {0.0f, 0.0f, 0.0f, 0.0f};
      acc[mt][j] = z;
    }

  const int row = t >> 3, jj = t & 7;       // staging: 8 threads per row
  const float* qrow = query   + (size_t)(m0 + row) * H_DIM;
  const float* crow = content + (size_t)(m0 + row) * H_DIM;
  char* abase = smem + row * 1024;

  #pragma unroll
  for (int h = 0; h < 2; h++) {
    // ---- stage A half h: k in [h*256, h*256+256), q|c, swizzled 16B granules
    // granule g = local k/8 in [0,32); byte = ((g ^ (row&7))<<4) + (fi&1)*8
    #pragma unroll
    for (int i = 0; i < 8; i++) {
      const int fi = i * 8 + jj;            // float4 index in [0,64)
      const int sw = (((fi >> 1) ^ (row & 7)) << 4) + (fi & 1) * 8;
      float4 fq = *(const float4*)(qrow + h * 256 + fi * 4);
      float4 fc = *(const float4*)(crow + h * 256 + fi * 4);
      uintx2 q2 = { cvt2(fq.x, fq.y), cvt2(fq.z, fq.w) };
      uintx2 c2 = { cvt2(fc.x, fc.y), cvt2(fc.z, fc.w) };
      *(uintx2*)(abase + sw) = q2;
      *(uintx2*)(abase + 512 + sw) = c2;
    }
    __syncthreads();                         // half staged

    // ---- 8 K-iters of BK=32 on this half ----
    #pragma unroll 2
    for (int it8 = 0; it8 < 8; ++it8) {
      const int it = h * 8 + it8;
      short8 aq[2], ac[2];
      #pragma unroll
      for (int mt = 0; mt < 2; mt++) {
        const int ar = mt * 16 + ln15;
        const int sw = ar * 1024 + ((((it8 * 4 + quad) ^ (ar & 7))) << 4);
        aq[mt] = *(const short8*)(smem + sw);
        ac[mt] = *(const short8*)(smem + sw + 512);
      }
      #pragma unroll
      for (int j = 0; j < 9; j++) {
        const int nt = wv * 9 + j;
        #pragma unroll
        for (int mt = 0; mt < 2; mt++) {
          short8 a = (nt >= 32) ? ac[mt] : aq[mt];
          acc[mt][j] = __builtin_amdgcn_mfma_f32_16x16x32_bf16(a, breg[j], acc[mt][j], 0, 0, 0);
        }
        if (it < 15)                         // rolling prefetch, next k-chunk
          breg[j] = *(const short8*)(bp[j] + (it + 1) * 32);
      }
    }
    __syncthreads();   // all waves done with this half (also guards lg overwrite)
  }

  // ---- dump biased logits to LDS (C/D layout: col=lane&15, row=quad*4+reg) ----
  #pragma unroll
  for (int j = 0; j < 9; j++) {
    int n = (wv * 9 + j) * 16 + ln15;
    #pragma unroll
    for (int mt = 0; mt < 2; mt++) {
      #pragma unroll
      for (int r = 0; r < 4; r++) {
        int rr = mt * 16 + quad * 4 + r;
        lg[rr * 584 + n] = f2b(acc[mt][j][r] + bias[j]);
      }
    }
  }
  cs[t] = 0.0f;
  if (t < 64) cp[t] = 0.0f;
  __syncthreads();

  const int r = t >> 3, c = t & 7;          // 8 threads per row
  unsigned short* lrow = lg + r * 584;

  // ---- read softmax: cols [0,256), normalized P written back in place ----
  {
    float v[32];
    #pragma unroll
    for (int ch = 0; ch < 4; ch++) {
      short8 u = *(const short8*)(lrow + c * 32 + ch * 8);
      #pragma unroll
      for (int e = 0; e < 8; e++) v[ch * 8 + e] = b2f((unsigned short)u[e]);
    }
    float mx = -3.0e38f;
    #pragma unroll
    for (int i = 0; i < 32; i++) mx = fmaxf(mx, v[i]);
    mx = fmaxf(mx, __shfl_xor(mx, 1));
    mx = fmaxf(mx, __shfl_xor(mx, 2));
    mx = fmaxf(mx, __shfl_xor(mx, 4));
    float sm = 0.0f;
    #pragma unroll
    for (int i = 0; i < 32; i++) { v[i] = __expf(v[i] - mx); sm += v[i]; }
    sm += __shfl_xor(sm, 1);
    sm += __shfl_xor(sm, 2);
    sm += __shfl_xor(sm, 4);
    float inv = 1.0f / sm;
    #pragma unroll
    for (int ch = 0; ch < 4; ch++) {
      short8 u;
      #pragma unroll
      for (int e = 0; e < 8; e++) u[e] = (short)f2b(v[ch * 8 + e] * inv);
      *(short8*)(lrow + c * 32 + ch * 8) = u;
    }
  }
  // ---- write softmax: cols [256,512), only column sums needed ----
  {
    float v[32];
    #pragma unroll
    for (int ch = 0; ch < 4; ch++) {
      short8 u = *(const short8*)(lrow + 256 + c * 32 + ch * 8);
      #pragma unroll
      for (int e = 0; e < 8; e++) v[ch * 8 + e] = b2f((unsigned short)u[e]);
    }
    float mx = -3.0e38f;
    #pragma unroll
    for (int i = 0; i < 32; i++) mx = fmaxf(mx, v[i]);
    mx = fmaxf(mx, __shfl_xor(mx, 1));
    mx = fmaxf(mx, __shfl_xor(mx, 2));
    mx = fmaxf(mx, __shfl_xor(mx, 4));
    float sm = 0.0f;
    #pragma unroll
    for (int i = 0; i < 32; i++) { v[i] = __expf(v[i] - mx); sm += v[i]; }
    sm += __shfl_xor(sm, 1);
    sm += __shfl_xor(sm, 2);
    sm += __shfl_xor(sm, 4);
    float inv = 1.0f / sm;
    #pragma unroll
    for (int i = 0; i < 32; i++) {          // reduce the wave's 8 rows
      float p = v[i] * inv;
      p += __shfl_xor(p, 8);
      p += __shfl_xor(p, 16);
      p += __shfl_xor(p, 32);
      v[i] = p;
    }
    if (ln < 8) {
      #pragma unroll
      for (int i = 0; i < 32; i++) atomicAdd(&cs[c * 32 + i], v[i]);
    }
  }
  // ---- processed-content partial sums: cols [512,576) ----
  {
    float v[8];
    short8 u = *(const short8*)(lrow + 512 + c * 8);
    #pragma unroll
    for (int e = 0; e < 8; e++) v[e] = b2f((unsigned short)u[e]);
    #pragma unroll
    for (int e = 0; e < 8; e++) {
      float p = v[e];
      p += __shfl_xor(p, 8);
      p += __shfl_xor(p, 16);
      p += __shfl_xor(p, 32);
      v[e] = p;
    }
    if (ln < 8) {
      #pragma unroll
      for (int e = 0; e < 8; e++) atomicAdd(&cp[c * 8 + e], v[e]);
    }
  }
  __syncthreads();

  // ---- PV: read_content = P @ memory; B-frags from L2-resident memT ----
  {
    int mt = wv & 1, nd0 = (wv >> 1) * 2;
    floatx4 ra[2];
    floatx4 z = {0.0f, 0.0f, 0.0f, 0.0f};
    ra[0] = z; ra[1] = z;
    #pragma unroll
    for (int ks = 0; ks < 8; ks++) {
      int s0 = ks * 32 + quad * 8;
      short8 a = *(const short8*)(lg + (mt * 16 + ln15) * 584 + s0);
      #pragma unroll
      for (int dt = 0; dt < 2; dt++) {
        short8 b = *(const short8*)(memT + ((nd0 + dt) * 16 + ln15) * 256 + s0);
        ra[dt] = __builtin_amdgcn_mfma_f32_16x16x32_bf16(a, b, ra[dt], 0, 0, 0);
      }
    }
    #pragma unroll
    for (int dt = 0; dt < 2; dt++)
      #pragma unroll
      for (int rr = 0; rr < 4; rr++) {
        int orow = m0 + mt * 16 + quad * 4 + rr;
        out[(size_t)orow * 64 + (nd0 + dt) * 16 + ln15] = ra[dt][rr];
      }
  }

  // block partials -> global accumulators
  atomicAdd(&w_sum[t], cs[t]);
  if (t < 64) atomicAdd(&c_sum[t], cp[t]);
}

__global__ void drcn_final(const float* __restrict__ memory, const float* __restrict__ age,
                           const float* __restrict__ w_sum, const float* __restrict__ c_sum,
                           float* __restrict__ out_mem, float* __restrict__ out_age) {
  int idx = blockIdx.x * 256 + threadIdx.x;   // 16384 = 256 slots * 64
  int s = idx >> 6, d = idx & 63;
  float wm = w_sum[s] * (1.0f / 65536.0f);
  bool act = wm > 0.01f;
  float cons = 1.0f / (1.0f + __expf(-age[s] * 0.1f));
  float alpha = act ? wm * cons : 0.0f;
  float cm = c_sum[d] * (1.0f / 65536.0f);
  out_mem[idx] = (1.0f - alpha) * memory[idx] + alpha * cm;
  if (d == 0) out_age[s] = age[s] + (act ? 1.0f : 0.0f);
}

extern "C" void kernel_launch(void* const* d_in, const int* in_sizes, int n_in,
                              void* d_out, int out_size, void* d_ws, size_t ws_size,
                              hipStream_t stream) {
  (void)in_sizes; (void)n_in; (void)out_size; (void)ws_size;
  const float* query     = (const float*)d_in[0];
  const float* content   = (const float*)d_in[1];
  const float* memory    = (const float*)d_in[2];
  const float* mem_age   = (const float*)d_in[3];
  const float* W_read    = (const float*)d_in[4];
  const float* b_read    = (const float*)d_in[5];
  const float* W_write   = (const float*)d_in[6];
  const float* b_write   = (const float*)d_in[7];
  const float* W_content = (const float*)d_in[8];
  const float* b_content = (const float*)d_in[9];
  float* out = (float*)d_out;
  char* ws = (char*)d_ws;
  unsigned short* Wt   = (unsigned short*)(ws + WS_WT);
  unsigned short* memT = (unsigned short*)(ws + WS_MEMT);
  float* bfull = (float*)(ws + WS_BFULL);
  float* w_sum = (float*)(ws + WS_WSUM);
  float* c_sum = (float*)(ws + WS_CSUM);

  drcn_init<<<1220, 256, 0, stream>>>(W_read, W_write, W_content, b_read, b_write,
                                      b_content, memory, Wt, memT, bfull, w_sum, c_sum);
  drcn_main<<<2048, 256, 0, stream>>>(query, content, Wt, bfull, memT, w_sum, c_sum, out);
  drcn_final<<<64, 256, 0, stream>>>(memory, mem_age, w_sum, c_sum,
                                     out + 4194304, out + 4210688);
}

// Round 4
// 414.088 us; speedup vs baseline: 1.5832x; 1.5832x over previous
//
#include <hip/hip_runtime.h>
#include <hip/hip_bf16.h>

// DenseRecurrentConsciousnessNet on MI355X (gfx950)
// B=65536, H=512, S=256, D=64.
// R6: R5's launch_bounds(256,4) forced a 64-VGPR allocation -> massive
// scratch spill in the K-loop (WRITE_SIZE 19MB -> 756MB, FETCH +400MB,
// dur 232 -> 457us). Live state needs ~130 regs (acc 72 + breg 36 + addrs).
// Fix: launch_bounds(256,2) — allocator lands ~100 VGPR (like R4), which
// still gives 4 waves/SIMD (alloc granule 128) and 4 blocks/CU with the
// 38.9KB LDS. Everything else identical to R5 (K-half A staging, direct
// B prefetch, verified epilogue).

typedef short short8 __attribute__((ext_vector_type(8)));
typedef float floatx4 __attribute__((ext_vector_type(4)));
typedef unsigned uintx2 __attribute__((ext_vector_type(2)));

#define H_DIM 512
#define BM 32

// ws byte offsets
#define WS_WT    0          // bf16 [576][512]  = 589824 B
#define WS_MEMT  589824     // bf16 [64][256]   = 32768 B
#define WS_BFULL 622592     // f32  [576]       = 2304 B
#define WS_WSUM  624896     // f32  [256]       = 1024 B
#define WS_CSUM  625920     // f32  [64]        = 256 B

__device__ __forceinline__ unsigned short f2b(float f) {
  unsigned u = __float_as_uint(f);
  u += 0x7fffu + ((u >> 16) & 1u);          // round-to-nearest-even
  return (unsigned short)(u >> 16);
}
__device__ __forceinline__ float b2f(unsigned short h) {
  return __uint_as_float(((unsigned)h) << 16);
}
__device__ __forceinline__ unsigned cvt2(float x, float y) {
  union { __hip_bfloat162 h; unsigned u; } c;
  c.h = __float22bfloat162_rn(make_float2(x, y));
  return c.u;
}

__global__ void drcn_init(const float* __restrict__ W_read, const float* __restrict__ W_write,
                          const float* __restrict__ W_content, const float* __restrict__ b_read,
                          const float* __restrict__ b_write, const float* __restrict__ b_content,
                          const float* __restrict__ memory,
                          unsigned short* __restrict__ Wt, unsigned short* __restrict__ memT,
                          float* __restrict__ bfull, float* __restrict__ w_sum,
                          float* __restrict__ c_sum) {
  int idx = blockIdx.x * 256 + threadIdx.x;
  if (idx < 294912) {                       // Wt[n][k] = W[k][n], bf16
    int n = idx >> 9, k = idx & 511;
    float v;
    if (n < 256)      v = W_read[k * 256 + n];
    else if (n < 512) v = W_write[k * 256 + (n - 256)];
    else              v = W_content[k * 64 + (n - 512)];
    Wt[idx] = f2b(v);
  } else if (idx < 311296) {                // memT[d][s] = memory[s][d], bf16
    int i = idx - 294912;
    int d = i >> 8, s = i & 255;
    memT[i] = f2b(memory[s * 64 + d]);
  } else if (idx < 311872) {                // packed bias [576]
    int n = idx - 311296;
    bfull[n] = (n < 256) ? b_read[n] : (n < 512 ? b_write[n - 256] : b_content[n - 512]);
  } else if (idx < 312192) {                // zero accumulators
    int i = idx - 311872;
    if (i < 256) w_sum[i] = 0.0f; else c_sum[i - 256] = 0.0f;
  }
}

__global__ __launch_bounds__(256, 2) void drcn_main(
    const float* __restrict__ query, const float* __restrict__ content,
    const unsigned short* __restrict__ Wt, const float* __restrict__ bfull,
    const unsigned short* __restrict__ memT, float* __restrict__ w_sum,
    float* __restrict__ c_sum, float* __restrict__ out) {
  // LDS phases:
  //   K-loop : A half-tile [32 rows][1024 B] = q(512B) | c(512B), swizzled.
  //   epilog : lg[32][584] bf16 (37376) | cs[256] f32 @37376 | cp[64] f32 @38400
  __shared__ __align__(16) char smem[38912];
  unsigned short* lg = (unsigned short*)smem;
  float* cs = (float*)(smem + 37376);
  float* cp = (float*)(smem + 38400);

  const int t = threadIdx.x;
  const int wv = t >> 6;
  const int ln = t & 63;
  const int ln15 = ln & 15;
  const int quad = ln >> 4;
  const int m0 = blockIdx.x * BM;

  // ---- B: direct global->VGPR, per-lane frag pointers + iter-0 loads ----
  // frag(j, it): Wt[(wv*9+j)*16 + ln15][it*32 + quad*8 .. +8]
  const unsigned short* bp[9];
  short8 breg[9];
  #pragma unroll
  for (int j = 0; j < 9; j++) {
    bp[j] = Wt + (size_t)(((wv * 9 + j) * 16 + ln15) * 512 + quad * 8);
    breg[j] = *(const short8*)bp[j];
  }

  float bias[9];
  #pragma unroll
  for (int j = 0; j < 9; j++) bias[j] = bfull[(wv * 9 + j) * 16 + ln15];

  floatx4 acc[2][9];
  #pragma unroll
  for (int mt = 0; mt < 2; mt++)
    #pragma unroll
    for (int j = 0; j < 9; j++) {
      floatx4 z = {0.0f, 0.0f, 0.0f, 0.0f};
      acc[mt][j] = z;
    }

  const int row = t >> 3, jj = t & 7;       // staging: 8 threads per row
  const float* qrow = query   + (size_t)(m0 + row) * H_DIM;
  const float* crow = content + (size_t)(m0 + row) * H_DIM;
  char* abase = smem + row * 1024;

  #pragma unroll
  for (int h = 0; h < 2; h++) {
    // ---- stage A half h: k in [h*256, h*256+256), q|c, swizzled 16B granules
    // granule g = local k/8 in [0,32); byte = ((g ^ (row&7))<<4) + (fi&1)*8
    #pragma unroll
    for (int i = 0; i < 8; i++) {
      const int fi = i * 8 + jj;            // float4 index in [0,64)
      const int sw = (((fi >> 1) ^ (row & 7)) << 4) + (fi & 1) * 8;
      float4 fq = *(const float4*)(qrow + h * 256 + fi * 4);
      float4 fc = *(const float4*)(crow + h * 256 + fi * 4);
      uintx2 q2 = { cvt2(fq.x, fq.y), cvt2(fq.z, fq.w) };
      uintx2 c2 = { cvt2(fc.x, fc.y), cvt2(fc.z, fc.w) };
      *(uintx2*)(abase + sw) = q2;
      *(uintx2*)(abase + 512 + sw) = c2;
    }
    __syncthreads();                         // half staged

    // ---- 8 K-iters of BK=32 on this half ----
    #pragma unroll 2
    for (int it8 = 0; it8 < 8; ++it8) {
      const int it = h * 8 + it8;
      short8 aq[2], ac[2];
      #pragma unroll
      for (int mt = 0; mt < 2; mt++) {
        const int ar = mt * 16 + ln15;
        const int sw = ar * 1024 + ((((it8 * 4 + quad) ^ (ar & 7))) << 4);
        aq[mt] = *(const short8*)(smem + sw);
        ac[mt] = *(const short8*)(smem + sw + 512);
      }
      #pragma unroll
      for (int j = 0; j < 9; j++) {
        const int nt = wv * 9 + j;
        #pragma unroll
        for (int mt = 0; mt < 2; mt++) {
          short8 a = (nt >= 32) ? ac[mt] : aq[mt];
          acc[mt][j] = __builtin_amdgcn_mfma_f32_16x16x32_bf16(a, breg[j], acc[mt][j], 0, 0, 0);
        }
        if (it < 15)                         // rolling prefetch, next k-chunk
          breg[j] = *(const short8*)(bp[j] + (it + 1) * 32);
      }
    }
    __syncthreads();   // all waves done with this half (also guards lg overwrite)
  }

  // ---- dump biased logits to LDS (C/D layout: col=lane&15, row=quad*4+reg) ----
  #pragma unroll
  for (int j = 0; j < 9; j++) {
    int n = (wv * 9 + j) * 16 + ln15;
    #pragma unroll
    for (int mt = 0; mt < 2; mt++) {
      #pragma unroll
      for (int r = 0; r < 4; r++) {
        int rr = mt * 16 + quad * 4 + r;
        lg[rr * 584 + n] = f2b(acc[mt][j][r] + bias[j]);
      }
    }
  }
  cs[t] = 0.0f;
  if (t < 64) cp[t] = 0.0f;
  __syncthreads();

  const int r = t >> 3, c = t & 7;          // 8 threads per row
  unsigned short* lrow = lg + r * 584;

  // ---- read softmax: cols [0,256), normalized P written back in place ----
  {
    float v[32];
    #pragma unroll
    for (int ch = 0; ch < 4; ch++) {
      short8 u = *(const short8*)(lrow + c * 32 + ch * 8);
      #pragma unroll
      for (int e = 0; e < 8; e++) v[ch * 8 + e] = b2f((unsigned short)u[e]);
    }
    float mx = -3.0e38f;
    #pragma unroll
    for (int i = 0; i < 32; i++) mx = fmaxf(mx, v[i]);
    mx = fmaxf(mx, __shfl_xor(mx, 1));
    mx = fmaxf(mx, __shfl_xor(mx, 2));
    mx = fmaxf(mx, __shfl_xor(mx, 4));
    float sm = 0.0f;
    #pragma unroll
    for (int i = 0; i < 32; i++) { v[i] = __expf(v[i] - mx); sm += v[i]; }
    sm += __shfl_xor(sm, 1);
    sm += __shfl_xor(sm, 2);
    sm += __shfl_xor(sm, 4);
    float inv = 1.0f / sm;
    #pragma unroll
    for (int ch = 0; ch < 4; ch++) {
      short8 u;
      #pragma unroll
      for (int e = 0; e < 8; e++) u[e] = (short)f2b(v[ch * 8 + e] * inv);
      *(short8*)(lrow + c * 32 + ch * 8) = u;
    }
  }
  // ---- write softmax: cols [256,512), only column sums needed ----
  {
    float v[32];
    #pragma unroll
    for (int ch = 0; ch < 4; ch++) {
      short8 u = *(const short8*)(lrow + 256 + c * 32 + ch * 8);
      #pragma unroll
      for (int e = 0; e < 8; e++) v[ch * 8 + e] = b2f((unsigned short)u[e]);
    }
    float mx = -3.0e38f;
    #pragma unroll
    for (int i = 0; i < 32; i++) mx = fmaxf(mx, v[i]);
    mx = fmaxf(mx, __shfl_xor(mx, 1));
    mx = fmaxf(mx, __shfl_xor(mx, 2));
    mx = fmaxf(mx, __shfl_xor(mx, 4));
    float sm = 0.0f;
    #pragma unroll
    for (int i = 0; i < 32; i++) { v[i] = __expf(v[i] - mx); sm += v[i]; }
    sm += __shfl_xor(sm, 1);
    sm += __shfl_xor(sm, 2);
    sm += __shfl_xor(sm, 4);
    float inv = 1.0f / sm;
    #pragma unroll
    for (int i = 0; i < 32; i++) {          // reduce the wave's 8 rows
      float p = v[i] * inv;
      p += __shfl_xor(p, 8);
      p += __shfl_xor(p, 16);
      p += __shfl_xor(p, 32);
      v[i] = p;
    }
    if (ln < 8) {
      #pragma unroll
      for (int i = 0; i < 32; i++) atomicAdd(&cs[c * 32 + i], v[i]);
    }
  }
  // ---- processed-content partial sums: cols [512,576) ----
  {
    float v[8];
    short8 u = *(const short8*)(lrow + 512 + c * 8);
    #pragma unroll
    for (int e = 0; e < 8; e++) v[e] = b2f((unsigned short)u[e]);
    #pragma unroll
    for (int e = 0; e < 8; e++) {
      float p = v[e];
      p += __shfl_xor(p, 8);
      p += __shfl_xor(p, 16);
      p += __shfl_xor(p, 32);
      v[e] = p;
    }
    if (ln < 8) {
      #pragma unroll
      for (int e = 0; e < 8; e++) atomicAdd(&cp[c * 8 + e], v[e]);
    }
  }
  __syncthreads();

  // ---- PV: read_content = P @ memory; B-frags from L2-resident memT ----
  {
    int mt = wv & 1, nd0 = (wv >> 1) * 2;
    floatx4 ra[2];
    floatx4 z = {0.0f, 0.0f, 0.0f, 0.0f};
    ra[0] = z; ra[1] = z;
    #pragma unroll
    for (int ks = 0; ks < 8; ks++) {
      int s0 = ks * 32 + quad * 8;
      short8 a = *(const short8*)(lg + (mt * 16 + ln15) * 584 + s0);
      #pragma unroll
      for (int dt = 0; dt < 2; dt++) {
        short8 b = *(const short8*)(memT + ((nd0 + dt) * 16 + ln15) * 256 + s0);
        ra[dt] = __builtin_amdgcn_mfma_f32_16x16x32_bf16(a, b, ra[dt], 0, 0, 0);
      }
    }
    #pragma unroll
    for (int dt = 0; dt < 2; dt++)
      #pragma unroll
      for (int rr = 0; rr < 4; rr++) {
        int orow = m0 + mt * 16 + quad * 4 + rr;
        out[(size_t)orow * 64 + (nd0 + dt) * 16 + ln15] = ra[dt][rr];
      }
  }

  // block partials -> global accumulators
  atomicAdd(&w_sum[t], cs[t]);
  if (t < 64) atomicAdd(&c_sum[t], cp[t]);
}

__global__ void drcn_final(const float* __restrict__ memory, const float* __restrict__ age,
                           const float* __restrict__ w_sum, const float* __restrict__ c_sum,
                           float* __restrict__ out_mem, float* __restrict__ out_age) {
  int idx = blockIdx.x * 256 + threadIdx.x;   // 16384 = 256 slots * 64
  int s = idx >> 6, d = idx & 63;
  float wm = w_sum[s] * (1.0f / 65536.0f);
  bool act = wm > 0.01f;
  float cons = 1.0f / (1.0f + __expf(-age[s] * 0.1f));
  float alpha = act ? wm * cons : 0.0f;
  float cm = c_sum[d] * (1.0f / 65536.0f);
  out_mem[idx] = (1.0f - alpha) * memory[idx] + alpha * cm;
  if (d == 0) out_age[s] = age[s] + (act ? 1.0f : 0.0f);
}

extern "C" void kernel_launch(void* const* d_in, const int* in_sizes, int n_in,
                              void* d_out, int out_size, void* d_ws, size_t ws_size,
                              hipStream_t stream) {
  (void)in_sizes; (void)n_in; (void)out_size; (void)ws_size;
  const float* query     = (const float*)d_in[0];
  const float* content   = (const float*)d_in[1];
  const float* memory    = (const float*)d_in[2];
  const float* mem_age   = (const float*)d_in[3];
  const float* W_read    = (const float*)d_in[4];
  const float* b_read    = (const float*)d_in[5];
  const float* W_write   = (const float*)d_in[6];
  const float* b_write   = (const float*)d_in[7];
  const float* W_content = (const float*)d_in[8];
  const float* b_content = (const float*)d_in[9];
  float* out = (float*)d_out;
  char* ws = (char*)d_ws;
  unsigned short* Wt   = (unsigned short*)(ws + WS_WT);
  unsigned short* memT = (unsigned short*)(ws + WS_MEMT);
  float* bfull = (float*)(ws + WS_BFULL);
  float* w_sum = (float*)(ws + WS_WSUM);
  float* c_sum = (float*)(ws + WS_CSUM);

  drcn_init<<<1220, 256, 0, stream>>>(W_read, W_write, W_content, b_read, b_write,
                                      b_content, memory, Wt, memT, bfull, w_sum, c_sum);
  drcn_main<<<2048, 256, 0, stream>>>(query, content, Wt, bfull, memT, w_sum, c_sum, out);
  drcn_final<<<64, 256, 0, stream>>>(memory, mem_age, w_sum, c_sum,
                                     out + 4194304, out + 4210688);
}